// Round 4
// baseline (429.847 us; speedup 1.0000x reference)
//
#include <hip/hip_runtime.h>
#include <hip/hip_bf16.h>
#include <math.h>

typedef __hip_bfloat16  bf16_t;
typedef __hip_bfloat162 bf162_t;
typedef __attribute__((ext_vector_type(8))) short  short8;   // 8 bf16 (4 VGPRs)
typedef __attribute__((ext_vector_type(4))) float  f32x4;

#define CDIM 128

static __device__ __forceinline__ float sigm(float x){ return 1.0f/(1.0f+__expf(-x)); }
static __device__ __forceinline__ float b2f(bf16_t v){ return __bfloat162float(v); }
static __device__ __forceinline__ short f2bf_s(float f){
    __hip_bfloat16 h = __float2bfloat16(f);
    return __builtin_bit_cast(short, h);
}

// ---------- 1. LSTM single step -> evolved GCN weight w_new [C,C] (f32) ----------
__global__ void k_lstm(const float* __restrict__ weight, const float* __restrict__ w_ih,
                       const float* __restrict__ b_ih,   const float* __restrict__ b_hh,
                       float* __restrict__ wnew){
    __shared__ float wrow[CDIM];
    const int r = blockIdx.x, j = threadIdx.x;
    wrow[j] = weight[r*CDIM + j];
    __syncthreads();
    const float4* wi = (const float4*)(w_ih + (size_t)j*CDIM);
    const float4* wg = (const float4*)(w_ih + (size_t)(2*CDIM + j)*CDIM);
    const float4* wo = (const float4*)(w_ih + (size_t)(3*CDIM + j)*CDIM);
    const float4* wr = (const float4*)wrow;
    float si = 0.f, sg = 0.f, so = 0.f;
    #pragma unroll 8
    for(int k = 0; k < CDIM/4; k++){
        float4 w4 = wr[k];
        float4 a = wi[k]; si += w4.x*a.x + w4.y*a.y + w4.z*a.z + w4.w*a.w;
        float4 b = wg[k]; sg += w4.x*b.x + w4.y*b.y + w4.z*b.z + w4.w*b.w;
        float4 c = wo[k]; so += w4.x*c.x + w4.y*c.y + w4.z*c.z + w4.w*c.w;
    }
    si += b_ih[j]        + b_hh[j];
    sg += b_ih[2*CDIM+j] + b_hh[2*CDIM+j];
    so += b_ih[3*CDIM+j] + b_hh[3*CDIM+j];
    float c = sigm(si)*tanhf(sg);            // f-gate * c0 = 0
    wnew[r*CDIM + j] = sigm(so)*tanhf(c);
}

// ---------- 1b. pack w_new into MFMA B-fragment layout (bf16) ----------
__global__ void k_pack(const float* __restrict__ wnew, short* __restrict__ wfrag){
    int id   = blockIdx.x*blockDim.x + threadIdx.x;   // 2048 total
    int lane = id & 63, n0 = (id >> 6) & 7, t = id >> 9;
    int quad = lane >> 4, mm = lane & 15;
    short8 v;
    #pragma unroll
    for(int j = 0; j < 8; j++)
        v[j] = f2bf_s(wnew[(32*t + quad*8 + j)*CDIM + 16*n0 + mm]);
    ((short8*)wfrag)[id] = v;
}

// ---------- 2. graph prep ----------
__global__ void k_init(int* __restrict__ deg, int* __restrict__ cursor, int* __restrict__ total, int n){
    int i = blockIdx.x*blockDim.x + threadIdx.x;
    if(i == 0) *total = 0;
    if(i < n){ deg[i] = 0; cursor[i] = 0; }
}

__global__ void k_count(const int* __restrict__ dst, int e, int* __restrict__ deg){
    int i = blockIdx.x*blockDim.x + threadIdx.x;
    if(i < e) atomicAdd(&deg[dst[i]], 1);
}

__global__ void k_off(const int* __restrict__ deg, float* __restrict__ dinv,
                      int* __restrict__ offs, int* __restrict__ total, int n){
    int i = blockIdx.x*blockDim.x + threadIdx.x;
    if(i < n){
        int d = deg[i];
        dinv[i] = rsqrtf((float)(d + 1));        // +1 self-loop
        offs[i] = atomicAdd(total, d);           // wave-aggregated scan by LLVM atomic optimizer
    }
}

__global__ void k_fill(const int* __restrict__ src, const int* __restrict__ dst, int e,
                       const int* __restrict__ offs, int* __restrict__ cursor, int* __restrict__ csr){
    int i = blockIdx.x*blockDim.x + threadIdx.x;
    if(i < e){
        int d = dst[i];
        int p = offs[d] + atomicAdd(&cursor[d], 1);
        csr[p] = src[i];
    }
}

// ---------- 2b. y[v] = bf16(dinv[v] * x[v])  (4 rows per 256-thread block) ----------
__global__ void k_scale(const float* __restrict__ x, const float* __restrict__ dinv,
                        bf16_t* __restrict__ y, int n){
    int row = blockIdx.x*4 + (threadIdx.x >> 6);
    if(row >= n) return;
    int lane = threadIdx.x & 63;
    float di = dinv[row];
    float2 v = ((const float2*)(x + (size_t)row*CDIM))[lane];
    bf162_t o; o.x = __float2bfloat16(di*v.x); o.y = __float2bfloat16(di*v.y);
    ((bf162_t*)(y + (size_t)row*CDIM))[lane] = o;
}

// ---------- 3. aggregate: agg[i] = bf16( dinv[i] * (y[i] + sum_{j in N(i)} y[j]) ) ----------
__global__ void k_agg(const bf16_t* __restrict__ y, const int* __restrict__ csr,
                      const int* __restrict__ offs, const int* __restrict__ deg,
                      const float* __restrict__ dinv, bf16_t* __restrict__ agg, int n){
    int gw   = (int)(((size_t)blockIdx.x*blockDim.x + threadIdx.x) >> 6); // one wave per node
    int lane = threadIdx.x & 63;
    if(gw >= n) return;
    const int   off = offs[gw];
    const int   cnt = deg[gw];
    const float di  = dinv[gw];
    bf162_t sv = ((const bf162_t*)(y + (size_t)gw*CDIM))[lane];
    float a0 = b2f(sv.x);
    float a1 = b2f(sv.y);
    for(int base = 0; base < cnt; base += 64){
        int m = cnt - base; if(m > 64) m = 64;
        int jid = 0;
        if(lane < m) jid = csr[off + base + lane];
        for(int k = 0; k < m; k++){
            int jj = __shfl(jid, k, 64);
            bf162_t v = ((const bf162_t*)(y + (size_t)jj*CDIM))[lane];
            a0 += b2f(v.x);
            a1 += b2f(v.y);
        }
    }
    a0 *= di; a1 *= di;
    bf162_t o; o.x = __float2bfloat16(a0); o.y = __float2bfloat16(a1);
    ((bf162_t*)(agg + (size_t)gw*CDIM))[lane] = o;
}

// ---------- 4. out = agg(bf16) @ W(bf16 frags) via MFMA, f32 out ----------
__global__ __launch_bounds__(256) void k_mgemm(const bf16_t* __restrict__ agg,
                                               const short* __restrict__ wfrag,
                                               float* __restrict__ out, int n){
    const int wid  = blockIdx.x*4 + (threadIdx.x >> 6);   // one wave per 16-row stripe
    const int row0 = wid*16;
    if(row0 >= n) return;
    const int lane = threadIdx.x & 63;
    const int m    = lane & 15, quad = lane >> 4;
    int arow = row0 + m; if(arow > n-1) arow = n-1;
    const short* ap = (const short*)agg + (size_t)arow*CDIM + quad*8;
    short8 a0 = *(const short8*)(ap);
    short8 a1 = *(const short8*)(ap + 32);
    short8 a2 = *(const short8*)(ap + 64);
    short8 a3 = *(const short8*)(ap + 96);
    const short8* bp = (const short8*)wfrag;
    float* orow = out + (size_t)(row0 + quad*4)*CDIM + m;
    const bool full = (row0 + 16 <= n);
    #pragma unroll
    for(int n0 = 0; n0 < 8; n0++){
        f32x4 acc = {0.f, 0.f, 0.f, 0.f};
        acc = __builtin_amdgcn_mfma_f32_16x16x32_bf16(a0, bp[(0*8+n0)*64 + lane], acc, 0, 0, 0);
        acc = __builtin_amdgcn_mfma_f32_16x16x32_bf16(a1, bp[(1*8+n0)*64 + lane], acc, 0, 0, 0);
        acc = __builtin_amdgcn_mfma_f32_16x16x32_bf16(a2, bp[(2*8+n0)*64 + lane], acc, 0, 0, 0);
        acc = __builtin_amdgcn_mfma_f32_16x16x32_bf16(a3, bp[(3*8+n0)*64 + lane], acc, 0, 0, 0);
        if(full){
            #pragma unroll
            for(int r = 0; r < 4; r++)
                orow[(size_t)r*CDIM + n0*16] = acc[r];
        } else {
            #pragma unroll
            for(int r = 0; r < 4; r++)
                if(row0 + quad*4 + r < n) orow[(size_t)r*CDIM + n0*16] = acc[r];
        }
    }
}

extern "C" void kernel_launch(void* const* d_in, const int* in_sizes, int n_in,
                              void* d_out, int out_size, void* d_ws, size_t ws_size,
                              hipStream_t stream){
    const float* x      = (const float*)d_in[0];
    const int*   ei     = (const int*)  d_in[1];
    const float* weight = (const float*)d_in[2];
    const float* w_ih   = (const float*)d_in[3];
    // d_in[4] = w_hh: zero forward contribution (h0 = 0)
    const float* b_ih   = (const float*)d_in[5];
    const float* b_hh   = (const float*)d_in[6];
    float* out = (float*)d_out;

    const int n = in_sizes[0]/CDIM;   // 100000
    const int e = in_sizes[1]/2;      // 1600000
    const int* srcp = ei;
    const int* dstp = ei + e;

    auto alignup = [](size_t v){ return (v + 255) & ~(size_t)255; };
    char*  base = (char*)d_ws;
    size_t o = 0;
    float*  wnew   = (float*) (base+o); o += alignup((size_t)CDIM*CDIM*sizeof(float));
    short*  wfrag  = (short*) (base+o); o += alignup((size_t)CDIM*CDIM*sizeof(short));
    int*    deg    = (int*)   (base+o); o += alignup((size_t)n*4);
    float*  dinv   = (float*) (base+o); o += alignup((size_t)n*4);
    int*    offs   = (int*)   (base+o); o += alignup((size_t)n*4);
    int*    cursor = (int*)   (base+o); o += alignup((size_t)n*4);
    int*    total  = (int*)   (base+o); o += alignup(256);
    int*    csr    = (int*)   (base+o); o += alignup((size_t)e*4);
    bf16_t* aggbuf = (bf16_t*)(base+o); // n*CDIM*2 bytes (fits: proven in R2/R3)

    // y = dinv .* x in bf16 lives in d_out (free until k_mgemm overwrites it last).
    bf16_t* y = (bf16_t*)d_out;         // 25.6 MB used of 51.2 MB

    const int nb = (n + 255)/256;
    const int eb = (e + 255)/256;
    const int rb = (n + 3)/4;                 // 4 rows/waves per 256-thread block
    const int gw = (n + 15)/16;               // k_mgemm: 16-row stripes
    const int gb = (gw + 3)/4;

    k_lstm <<<CDIM, CDIM, 0, stream>>>(weight, w_ih, b_ih, b_hh, wnew);
    k_pack <<<8, 256, 0, stream>>>(wnew, wfrag);
    k_init <<<nb, 256, 0, stream>>>(deg, cursor, total, n);
    k_count<<<eb, 256, 0, stream>>>(dstp, e, deg);
    k_off  <<<nb, 256, 0, stream>>>(deg, dinv, offs, total, n);
    k_scale<<<rb, 256, 0, stream>>>(x, dinv, y, n);
    k_fill <<<eb, 256, 0, stream>>>(srcp, dstp, e, offs, cursor, csr);
    k_agg  <<<rb, 256, 0, stream>>>(y, csr, offs, deg, dinv, aggbuf, n);
    k_mgemm<<<gb, 256, 0, stream>>>(aggbuf, wfrag, out, n);
}

// Round 6
// 404.028 us; speedup vs baseline: 1.0639x; 1.0639x over previous
//
#include <hip/hip_runtime.h>
#include <hip/hip_bf16.h>
#include <math.h>

typedef __hip_bfloat16  bf16_t;
typedef __attribute__((ext_vector_type(8))) short  short8;   // 8 bf16 (4 VGPRs)
typedef __attribute__((ext_vector_type(4))) float  f32x4;

#define CDIM 128

static __device__ __forceinline__ float sigm(float x){ return 1.0f/(1.0f+__expf(-x)); }
static __device__ __forceinline__ float bflo(unsigned u){ return __builtin_bit_cast(float, u << 16); }
static __device__ __forceinline__ float bfhi(unsigned u){ return __builtin_bit_cast(float, u & 0xffff0000u); }
static __device__ __forceinline__ unsigned short f2bf_u(float f){
    __hip_bfloat16 h = __float2bfloat16(f);
    return __builtin_bit_cast(unsigned short, h);
}
static __device__ __forceinline__ unsigned packbf(float a, float b){
    return (unsigned)f2bf_u(a) | ((unsigned)f2bf_u(b) << 16);
}
static __device__ __forceinline__ short f2bf_s(float f){
    return (short)f2bf_u(f);
}

// ---------- 1. LSTM single step -> w_new, written DIRECTLY in MFMA B-frag layout (bf16) ----------
// wfrag short index: ((t*8+n0)*64 + quad*16+mm)*8 + jj  <=>  B[k=32t+quad*8+jj][n=n0*16+mm]
__global__ void k_lstm(const float* __restrict__ weight, const float* __restrict__ w_ih,
                       const float* __restrict__ b_ih,   const float* __restrict__ b_hh,
                       short* __restrict__ wfrag){
    __shared__ float wrow[CDIM];
    const int r = blockIdx.x, j = threadIdx.x;
    wrow[j] = weight[r*CDIM + j];
    __syncthreads();
    const float4* wi = (const float4*)(w_ih + (size_t)j*CDIM);
    const float4* wg = (const float4*)(w_ih + (size_t)(2*CDIM + j)*CDIM);
    const float4* wo = (const float4*)(w_ih + (size_t)(3*CDIM + j)*CDIM);
    const float4* wr = (const float4*)wrow;
    float si = 0.f, sg = 0.f, so = 0.f;
    #pragma unroll 8
    for(int k = 0; k < CDIM/4; k++){
        float4 w4 = wr[k];
        float4 a = wi[k]; si += w4.x*a.x + w4.y*a.y + w4.z*a.z + w4.w*a.w;
        float4 b = wg[k]; sg += w4.x*b.x + w4.y*b.y + w4.z*b.z + w4.w*b.w;
        float4 c = wo[k]; so += w4.x*c.x + w4.y*c.y + w4.z*c.z + w4.w*c.w;
    }
    si += b_ih[j]        + b_hh[j];
    sg += b_ih[2*CDIM+j] + b_hh[2*CDIM+j];
    so += b_ih[3*CDIM+j] + b_hh[3*CDIM+j];
    float c  = sigm(si)*tanhf(sg);           // f-gate * c0 = 0
    float wv = sigm(so)*tanhf(c);
    const int t = r >> 5, quad = (r >> 3) & 3, jj = r & 7;   // uniform per block
    const int n0 = j >> 4, mm = j & 15;
    wfrag[((size_t)((t*8 + n0)*64 + quad*16 + mm))*8 + jj] = f2bf_s(wv);
}

// ---------- 2. graph prep ----------
__global__ void k_count(const int* __restrict__ dst, int e, int* __restrict__ deg){
    int i = blockIdx.x*blockDim.x + threadIdx.x;
    if(i < e) atomicAdd(&deg[dst[i]], 1);
}

// dinv/offs (wave-aggregated atomic scan) + y = bf16(dinv .* x) for this block's 256 nodes
__global__ __launch_bounds__(256) void k_offscale(const float* __restrict__ x,
        const int* __restrict__ deg, int* __restrict__ total,
        float* __restrict__ dinv, int* __restrict__ offs, bf16_t* __restrict__ y, int n){
    __shared__ float sdinv[256];
    const int base = blockIdx.x*256;
    const int t = threadIdx.x;
    const int i = base + t;
    float dv = 0.f;
    if(i < n){
        int d = deg[i];
        dv = rsqrtf((float)(d + 1));          // +1 self-loop
        dinv[i] = dv;
        offs[i] = atomicAdd(total, d);        // LLVM wave-aggregates (uniform addr, varying val)
    }
    sdinv[t] = dv;
    __syncthreads();
    const int wid = t >> 6, lane = t & 63;
    for(int r = wid; r < 256; r += 4){
        int row = base + r;
        if(row >= n) break;
        float di = sdinv[r];
        float2 v = ((const float2*)(x + (size_t)row*CDIM))[lane];
        ((unsigned*)(y + (size_t)row*CDIM))[lane] = packbf(di*v.x, di*v.y);
    }
}

__global__ void k_fill(const int* __restrict__ src, const int* __restrict__ dst, int e,
                       const int* __restrict__ offs, int* __restrict__ cursor, int* __restrict__ csr){
    int i = blockIdx.x*blockDim.x + threadIdx.x;
    if(i < e){
        int d = dst[i];
        int p = offs[d] + atomicAdd(&cursor[d], 1);
        csr[p] = src[i];
    }
}

// ---------- 3. aggregate: agg[i] = bf16( dinv[i] * (y[i] + sum_{j in N(i)} y[j]) ) ----------
// One wave per node; quad q handles neighbor (k+q); lane covers 8 features (16 B).
// 8 independent row-loads in flight per wave (4 quads x unroll 2).
__global__ __launch_bounds__(256) void k_agg(const bf16_t* __restrict__ y, const int* __restrict__ csr,
                      const int* __restrict__ offs, const int* __restrict__ deg,
                      const float* __restrict__ dinv, bf16_t* __restrict__ agg, int n){
    const int node = (int)(((size_t)blockIdx.x*256 + threadIdx.x) >> 6);
    if(node >= n) return;
    const int lane = threadIdx.x & 63;
    const int q = lane >> 4, f = lane & 15;
    const int   off = offs[node];
    const int   cnt = deg[node];
    const float di  = dinv[node];
    const uint4* yrow = (const uint4*)y;               // 16 uint4 per row
    uint4 sv = yrow[(size_t)node*16 + f];              // self row
    float acc[8];
    #pragma unroll
    for(int i = 0; i < 8; i++) acc[i] = 0.f;
    for(int base = 0; base < cnt; base += 64){
        int m = cnt - base; if(m > 64) m = 64;
        int jid = (lane < m) ? csr[off + base + lane] : 0;
        for(int k = 0; k < m; k += 8){
            int e0 = k + q, e1 = k + 4 + q;
            int j0 = __shfl(jid, e0, 64);
            int j1 = __shfl(jid, e1, 64);
            if(e0 < m){
                uint4 v = yrow[(size_t)j0*16 + f];
                acc[0] += bflo(v.x); acc[1] += bfhi(v.x);
                acc[2] += bflo(v.y); acc[3] += bfhi(v.y);
                acc[4] += bflo(v.z); acc[5] += bfhi(v.z);
                acc[6] += bflo(v.w); acc[7] += bfhi(v.w);
            }
            if(e1 < m){
                uint4 v = yrow[(size_t)j1*16 + f];
                acc[0] += bflo(v.x); acc[1] += bfhi(v.x);
                acc[2] += bflo(v.y); acc[3] += bfhi(v.y);
                acc[4] += bflo(v.z); acc[5] += bfhi(v.z);
                acc[6] += bflo(v.w); acc[7] += bfhi(v.w);
            }
        }
    }
    #pragma unroll
    for(int i = 0; i < 8; i++){
        acc[i] += __shfl_xor(acc[i], 16, 64);
        acc[i] += __shfl_xor(acc[i], 32, 64);
    }
    if(q == 0){
        uint4 o;
        o.x = packbf(di*(acc[0] + bflo(sv.x)), di*(acc[1] + bfhi(sv.x)));
        o.y = packbf(di*(acc[2] + bflo(sv.y)), di*(acc[3] + bfhi(sv.y)));
        o.z = packbf(di*(acc[4] + bflo(sv.z)), di*(acc[5] + bfhi(sv.z)));
        o.w = packbf(di*(acc[6] + bflo(sv.w)), di*(acc[7] + bfhi(sv.w)));
        ((uint4*)agg)[(size_t)node*16 + f] = o;
    }
}

// ---------- 4. out = agg(bf16) @ W(bf16 frags) via MFMA, f32 out ----------
__global__ __launch_bounds__(256) void k_mgemm(const bf16_t* __restrict__ agg,
                                               const short* __restrict__ wfrag,
                                               float* __restrict__ out, int n){
    const int wid  = blockIdx.x*4 + (threadIdx.x >> 6);   // one wave per 16-row stripe
    const int row0 = wid*16;
    if(row0 >= n) return;
    const int lane = threadIdx.x & 63;
    const int m    = lane & 15, quad = lane >> 4;
    int arow = row0 + m; if(arow > n-1) arow = n-1;
    const short* ap = (const short*)agg + (size_t)arow*CDIM + quad*8;
    short8 a0 = *(const short8*)(ap);
    short8 a1 = *(const short8*)(ap + 32);
    short8 a2 = *(const short8*)(ap + 64);
    short8 a3 = *(const short8*)(ap + 96);
    const short8* bp = (const short8*)wfrag;
    float* orow = out + (size_t)(row0 + quad*4)*CDIM + m;
    const bool full = (row0 + 16 <= n);
    #pragma unroll
    for(int n0 = 0; n0 < 8; n0++){
        f32x4 acc = {0.f, 0.f, 0.f, 0.f};
        acc = __builtin_amdgcn_mfma_f32_16x16x32_bf16(a0, bp[(0*8+n0)*64 + lane], acc, 0, 0, 0);
        acc = __builtin_amdgcn_mfma_f32_16x16x32_bf16(a1, bp[(1*8+n0)*64 + lane], acc, 0, 0, 0);
        acc = __builtin_amdgcn_mfma_f32_16x16x32_bf16(a2, bp[(2*8+n0)*64 + lane], acc, 0, 0, 0);
        acc = __builtin_amdgcn_mfma_f32_16x16x32_bf16(a3, bp[(3*8+n0)*64 + lane], acc, 0, 0, 0);
        if(full){
            #pragma unroll
            for(int r = 0; r < 4; r++)
                orow[(size_t)r*CDIM + n0*16] = acc[r];
        } else {
            #pragma unroll
            for(int r = 0; r < 4; r++)
                if(row0 + quad*4 + r < n) orow[(size_t)r*CDIM + n0*16] = acc[r];
        }
    }
}

extern "C" void kernel_launch(void* const* d_in, const int* in_sizes, int n_in,
                              void* d_out, int out_size, void* d_ws, size_t ws_size,
                              hipStream_t stream){
    const float* x      = (const float*)d_in[0];
    const int*   ei     = (const int*)  d_in[1];
    const float* weight = (const float*)d_in[2];
    const float* w_ih   = (const float*)d_in[3];
    // d_in[4] = w_hh: zero forward contribution (h0 = 0)
    const float* b_ih   = (const float*)d_in[5];
    const float* b_hh   = (const float*)d_in[6];
    float* out = (float*)d_out;

    const int n = in_sizes[0]/CDIM;   // 100000
    const int e = in_sizes[1]/2;      // 1600000
    const int* srcp = ei;
    const int* dstp = ei + e;

    auto alignup = [](size_t v){ return (v + 255) & ~(size_t)255; };
    char*  base = (char*)d_ws;
    size_t o = 0;
    short*  wfrag  = (short*) (base+o); o += alignup((size_t)CDIM*CDIM*sizeof(short));
    int*    deg    = (int*)   (base+o); o += alignup((size_t)n*4);      // |
    int*    cursor = (int*)   (base+o); o += alignup((size_t)n*4);      // | contiguous zero region
    int*    total  = (int*)   (base+o); o += alignup(256);              // |
    size_t  zbytes = (size_t)((char*)(base+o) - (char*)deg);
    float*  dinv   = (float*) (base+o); o += alignup((size_t)n*4);
    int*    offs   = (int*)   (base+o); o += alignup((size_t)n*4);
    int*    csr    = (int*)   (base+o); o += alignup((size_t)e*4);
    bf16_t* aggbuf = (bf16_t*)(base+o); // n*CDIM*2 bytes (fits: proven in R2-R4)

    // y = dinv .* x in bf16 lives in d_out (free until k_mgemm overwrites it last).
    bf16_t* y = (bf16_t*)d_out;         // 25.6 MB used of 51.2 MB

    const int eb = (e + 255)/256;
    const int nb = (n + 255)/256;
    const int rb = (n + 3)/4;                 // k_agg: 4 waves (nodes) per block
    const int gw = (n + 15)/16;               // k_mgemm: 16-row stripes
    const int gb = (gw + 3)/4;

    (void)hipMemsetAsync(deg, 0, zbytes, stream);   // deg, cursor, total = 0
    k_lstm    <<<CDIM, CDIM, 0, stream>>>(weight, w_ih, b_ih, b_hh, wfrag);
    k_count   <<<eb, 256, 0, stream>>>(dstp, e, deg);
    k_offscale<<<nb, 256, 0, stream>>>(x, deg, total, dinv, offs, y, n);
    k_fill    <<<eb, 256, 0, stream>>>(srcp, dstp, e, offs, cursor, csr);
    k_agg     <<<rb, 256, 0, stream>>>(y, csr, offs, deg, dinv, aggbuf, n);
    k_mgemm   <<<gb, 256, 0, stream>>>(aggbuf, wfrag, out, n);
}

// Round 7
// 390.104 us; speedup vs baseline: 1.1019x; 1.0357x over previous
//
#include <hip/hip_runtime.h>
#include <hip/hip_bf16.h>
#include <math.h>

typedef __hip_bfloat16  bf16_t;
typedef __attribute__((ext_vector_type(8))) short  short8;   // 8 bf16 (4 VGPRs)
typedef __attribute__((ext_vector_type(4))) float  f32x4;

#define CDIM 128

static __device__ __forceinline__ float sigm(float x){ return 1.0f/(1.0f+__expf(-x)); }
static __device__ __forceinline__ float bflo(unsigned u){ return __builtin_bit_cast(float, u << 16); }
static __device__ __forceinline__ float bfhi(unsigned u){ return __builtin_bit_cast(float, u & 0xffff0000u); }
static __device__ __forceinline__ unsigned short f2bf_u(float f){
    __hip_bfloat16 h = __float2bfloat16(f);
    return __builtin_bit_cast(unsigned short, h);
}
static __device__ __forceinline__ unsigned packbf(float a, float b){
    return (unsigned)f2bf_u(a) | ((unsigned)f2bf_u(b) << 16);
}
static __device__ __forceinline__ short f2bf_s(float f){
    return (short)f2bf_u(f);
}

// ---------- 1. LSTM single step -> w_new, written DIRECTLY in MFMA B-frag layout (bf16) ----------
// wfrag short index: ((t*8+n0)*64 + quad*16+mm)*8 + jj  <=>  B[k=32t+quad*8+jj][n=n0*16+mm]
__global__ void k_lstm(const float* __restrict__ weight, const float* __restrict__ w_ih,
                       const float* __restrict__ b_ih,   const float* __restrict__ b_hh,
                       short* __restrict__ wfrag){
    __shared__ float wrow[CDIM];
    const int r = blockIdx.x, j = threadIdx.x;
    wrow[j] = weight[r*CDIM + j];
    __syncthreads();
    const float4* wi = (const float4*)(w_ih + (size_t)j*CDIM);
    const float4* wg = (const float4*)(w_ih + (size_t)(2*CDIM + j)*CDIM);
    const float4* wo = (const float4*)(w_ih + (size_t)(3*CDIM + j)*CDIM);
    const float4* wr = (const float4*)wrow;
    float si = 0.f, sg = 0.f, so = 0.f;
    #pragma unroll 8
    for(int k = 0; k < CDIM/4; k++){
        float4 w4 = wr[k];
        float4 a = wi[k]; si += w4.x*a.x + w4.y*a.y + w4.z*a.z + w4.w*a.w;
        float4 b = wg[k]; sg += w4.x*b.x + w4.y*b.y + w4.z*b.z + w4.w*b.w;
        float4 c = wo[k]; so += w4.x*c.x + w4.y*c.y + w4.z*c.z + w4.w*c.w;
    }
    si += b_ih[j]        + b_hh[j];
    sg += b_ih[2*CDIM+j] + b_hh[2*CDIM+j];
    so += b_ih[3*CDIM+j] + b_hh[3*CDIM+j];
    float c  = sigm(si)*tanhf(sg);           // f-gate * c0 = 0
    float wv = sigm(so)*tanhf(c);
    const int t = r >> 5, quad = (r >> 3) & 3, jj = r & 7;   // uniform per block
    const int n0 = j >> 4, mm = j & 15;
    wfrag[((size_t)((t*8 + n0)*64 + quad*16 + mm))*8 + jj] = f2bf_s(wv);
}

// ---------- 2. graph prep — XCD-partitioned by dst range ----------
// blockIdx & 7 selects the node-range group; round-robin dispatch puts each group
// on one XCD, so deg/cursor atomics and csr-line writes stay in ONE L2 (no cross-XCD
// line bouncing -> no 64B-per-4B writeback amplification). Correctness does not
// depend on the mapping (device-scope atomics).
__global__ __launch_bounds__(256) void k_count(const int* __restrict__ dst, int e,
                                               int* __restrict__ deg, int nper){
    const int grp  = blockIdx.x & 7;
    const int lo   = grp*nper, hi = lo + nper;
    const int step = (gridDim.x >> 3)*256;
    for(int i = (blockIdx.x >> 3)*256 + threadIdx.x; i < e; i += step){
        int d = dst[i];
        if(d >= lo && d < hi) atomicAdd(&deg[d], 1);
    }
}

__global__ __launch_bounds__(256) void k_fill(const int* __restrict__ src, const int* __restrict__ dst,
                                              int e, const int* __restrict__ offs,
                                              int* __restrict__ cursor, int* __restrict__ csr, int nper){
    const int grp  = blockIdx.x & 7;
    const int lo   = grp*nper, hi = lo + nper;
    const int step = (gridDim.x >> 3)*256;
    for(int i = (blockIdx.x >> 3)*256 + threadIdx.x; i < e; i += step){
        int d = dst[i];
        if(d >= lo && d < hi){
            int p = offs[d] + atomicAdd(&cursor[d], 1);
            csr[p] = src[i];
        }
    }
}

// dinv/offs (wave-aggregated atomic scan) + y = bf16(dinv .* x) for this block's 256 nodes
__global__ __launch_bounds__(256) void k_offscale(const float* __restrict__ x,
        const int* __restrict__ deg, int* __restrict__ total,
        float* __restrict__ dinv, int* __restrict__ offs, bf16_t* __restrict__ y, int n){
    __shared__ float sdinv[256];
    const int base = blockIdx.x*256;
    const int t = threadIdx.x;
    const int i = base + t;
    float dv = 0.f;
    if(i < n){
        int d = deg[i];
        dv = rsqrtf((float)(d + 1));          // +1 self-loop
        dinv[i] = dv;
        offs[i] = atomicAdd(total, d);        // LLVM wave-aggregates (uniform addr, varying val)
    }
    sdinv[t] = dv;
    __syncthreads();
    const int wid = t >> 6, lane = t & 63;
    for(int r = wid; r < 256; r += 4){
        int row = base + r;
        if(row >= n) break;
        float di = sdinv[r];
        float2 v = ((const float2*)(x + (size_t)row*CDIM))[lane];
        ((unsigned*)(y + (size_t)row*CDIM))[lane] = packbf(di*v.x, di*v.y);
    }
}

// ---------- 3. aggregate: agg[i] = bf16( dinv[i] * (y[i] + sum_{j in N(i)} y[j]) ) ----------
// One wave per node; quad q handles neighbor (k+q); lane covers 8 features (16 B).
// 8 independent row-loads in flight per wave (4 quads x unroll 2).
__global__ __launch_bounds__(256) void k_agg(const bf16_t* __restrict__ y, const int* __restrict__ csr,
                      const int* __restrict__ offs, const int* __restrict__ deg,
                      const float* __restrict__ dinv, bf16_t* __restrict__ agg, int n){
    const int node = (int)(((size_t)blockIdx.x*256 + threadIdx.x) >> 6);
    if(node >= n) return;
    const int lane = threadIdx.x & 63;
    const int q = lane >> 4, f = lane & 15;
    const int   off = offs[node];
    const int   cnt = deg[node];
    const float di  = dinv[node];
    const uint4* yrow = (const uint4*)y;               // 16 uint4 per row
    uint4 sv = yrow[(size_t)node*16 + f];              // self row
    float acc[8];
    #pragma unroll
    for(int i = 0; i < 8; i++) acc[i] = 0.f;
    for(int base = 0; base < cnt; base += 64){
        int m = cnt - base; if(m > 64) m = 64;
        int jid = (lane < m) ? csr[off + base + lane] : 0;
        for(int k = 0; k < m; k += 8){
            int e0 = k + q, e1 = k + 4 + q;
            int j0 = __shfl(jid, e0, 64);
            int j1 = __shfl(jid, e1, 64);
            if(e0 < m){
                uint4 v = yrow[(size_t)j0*16 + f];
                acc[0] += bflo(v.x); acc[1] += bfhi(v.x);
                acc[2] += bflo(v.y); acc[3] += bfhi(v.y);
                acc[4] += bflo(v.z); acc[5] += bfhi(v.z);
                acc[6] += bflo(v.w); acc[7] += bfhi(v.w);
            }
            if(e1 < m){
                uint4 v = yrow[(size_t)j1*16 + f];
                acc[0] += bflo(v.x); acc[1] += bfhi(v.x);
                acc[2] += bflo(v.y); acc[3] += bfhi(v.y);
                acc[4] += bflo(v.z); acc[5] += bfhi(v.z);
                acc[6] += bflo(v.w); acc[7] += bfhi(v.w);
            }
        }
    }
    #pragma unroll
    for(int i = 0; i < 8; i++){
        acc[i] += __shfl_xor(acc[i], 16, 64);
        acc[i] += __shfl_xor(acc[i], 32, 64);
    }
    if(q == 0){
        uint4 o;
        o.x = packbf(di*(acc[0] + bflo(sv.x)), di*(acc[1] + bfhi(sv.x)));
        o.y = packbf(di*(acc[2] + bflo(sv.y)), di*(acc[3] + bfhi(sv.y)));
        o.z = packbf(di*(acc[4] + bflo(sv.z)), di*(acc[5] + bfhi(sv.z)));
        o.w = packbf(di*(acc[6] + bflo(sv.w)), di*(acc[7] + bfhi(sv.w)));
        ((uint4*)agg)[(size_t)node*16 + f] = o;
    }
}

// ---------- 4. out = agg(bf16) @ W(bf16 frags) via MFMA, f32 out ----------
__global__ __launch_bounds__(256) void k_mgemm(const bf16_t* __restrict__ agg,
                                               const short* __restrict__ wfrag,
                                               float* __restrict__ out, int n){
    const int wid  = blockIdx.x*4 + (threadIdx.x >> 6);   // one wave per 16-row stripe
    const int row0 = wid*16;
    if(row0 >= n) return;
    const int lane = threadIdx.x & 63;
    const int m    = lane & 15, quad = lane >> 4;
    int arow = row0 + m; if(arow > n-1) arow = n-1;
    const short* ap = (const short*)agg + (size_t)arow*CDIM + quad*8;
    short8 a0 = *(const short8*)(ap);
    short8 a1 = *(const short8*)(ap + 32);
    short8 a2 = *(const short8*)(ap + 64);
    short8 a3 = *(const short8*)(ap + 96);
    const short8* bp = (const short8*)wfrag;
    float* orow = out + (size_t)(row0 + quad*4)*CDIM + m;
    const bool full = (row0 + 16 <= n);
    #pragma unroll
    for(int n0 = 0; n0 < 8; n0++){
        f32x4 acc = {0.f, 0.f, 0.f, 0.f};
        acc = __builtin_amdgcn_mfma_f32_16x16x32_bf16(a0, bp[(0*8+n0)*64 + lane], acc, 0, 0, 0);
        acc = __builtin_amdgcn_mfma_f32_16x16x32_bf16(a1, bp[(1*8+n0)*64 + lane], acc, 0, 0, 0);
        acc = __builtin_amdgcn_mfma_f32_16x16x32_bf16(a2, bp[(2*8+n0)*64 + lane], acc, 0, 0, 0);
        acc = __builtin_amdgcn_mfma_f32_16x16x32_bf16(a3, bp[(3*8+n0)*64 + lane], acc, 0, 0, 0);
        if(full){
            #pragma unroll
            for(int r = 0; r < 4; r++)
                orow[(size_t)r*CDIM + n0*16] = acc[r];
        } else {
            #pragma unroll
            for(int r = 0; r < 4; r++)
                if(row0 + quad*4 + r < n) orow[(size_t)r*CDIM + n0*16] = acc[r];
        }
    }
}

extern "C" void kernel_launch(void* const* d_in, const int* in_sizes, int n_in,
                              void* d_out, int out_size, void* d_ws, size_t ws_size,
                              hipStream_t stream){
    const float* x      = (const float*)d_in[0];
    const int*   ei     = (const int*)  d_in[1];
    const float* weight = (const float*)d_in[2];
    const float* w_ih   = (const float*)d_in[3];
    // d_in[4] = w_hh: zero forward contribution (h0 = 0)
    const float* b_ih   = (const float*)d_in[5];
    const float* b_hh   = (const float*)d_in[6];
    float* out = (float*)d_out;

    const int n = in_sizes[0]/CDIM;   // 100000
    const int e = in_sizes[1]/2;      // 1600000
    const int* srcp = ei;
    const int* dstp = ei + e;

    auto alignup = [](size_t v){ return (v + 255) & ~(size_t)255; };
    char*  base = (char*)d_ws;
    size_t o = 0;
    short*  wfrag  = (short*) (base+o); o += alignup((size_t)CDIM*CDIM*sizeof(short));
    int*    deg    = (int*)   (base+o); o += alignup((size_t)n*4);      // |
    int*    cursor = (int*)   (base+o); o += alignup((size_t)n*4);      // | contiguous zero region
    int*    total  = (int*)   (base+o); o += alignup(256);              // |
    size_t  zbytes = (size_t)((char*)(base+o) - (char*)deg);
    float*  dinv   = (float*) (base+o); o += alignup((size_t)n*4);
    int*    offs   = (int*)   (base+o); o += alignup((size_t)n*4);
    int*    csr    = (int*)   (base+o); o += alignup((size_t)e*4);
    bf16_t* aggbuf = (bf16_t*)(base+o); // n*CDIM*2 bytes (fits: proven in R2-R6)

    // y = dinv .* x in bf16 lives in d_out (free until k_mgemm overwrites it last).
    bf16_t* y = (bf16_t*)d_out;         // 25.6 MB used of 51.2 MB

    const int nper = (n + 7)/8;               // dst-range per XCD group
    const int pb = 2048;                      // 256 blocks per group
    const int nb = (n + 255)/256;
    const int rb = (n + 3)/4;                 // k_agg: 4 waves (nodes) per block
    const int gw = (n + 15)/16;               // k_mgemm: 16-row stripes
    const int gb = (gw + 3)/4;

    (void)hipMemsetAsync(deg, 0, zbytes, stream);   // deg, cursor, total = 0
    k_lstm    <<<CDIM, CDIM, 0, stream>>>(weight, w_ih, b_ih, b_hh, wfrag);
    k_count   <<<pb, 256, 0, stream>>>(dstp, e, deg, nper);
    k_offscale<<<nb, 256, 0, stream>>>(x, deg, total, dinv, offs, y, n);
    k_fill    <<<pb, 256, 0, stream>>>(srcp, dstp, e, offs, cursor, csr, nper);
    k_agg     <<<rb, 256, 0, stream>>>(y, csr, offs, deg, dinv, aggbuf, n);
    k_mgemm   <<<gb, 256, 0, stream>>>(aggbuf, wfrag, out, n);
}